// Round 1
// baseline (7064.161 us; speedup 1.0000x reference)
//
#include <hip/hip_runtime.h>
#include <hip/hip_bf16.h>

#define Bsz 256
#define Nd  512
#define Hd  2048
#define Td  64

typedef __attribute__((ext_vector_type(8))) short short8;
typedef __attribute__((ext_vector_type(4))) float f32x4;

#define LDU 72   // padded LDS stride (elements) for BK=64 tiles: 144B rows, 16B aligned, conflict-light

static __device__ __forceinline__ unsigned short f2bf(float x) {
  unsigned u = __builtin_bit_cast(unsigned, x);
  unsigned r = 0x7FFFu + ((u >> 16) & 1u);   // RNE
  u += r;
  return (unsigned short)(u >> 16);
}

static __device__ __forceinline__ short8 pack_bf8(f32x4 a, f32x4 b) {
  short8 s;
  s[0] = (short)f2bf(a[0]); s[1] = (short)f2bf(a[1]);
  s[2] = (short)f2bf(a[2]); s[3] = (short)f2bf(a[3]);
  s[4] = (short)f2bf(b[0]); s[5] = (short)f2bf(b[1]);
  s[6] = (short)f2bf(b[2]); s[7] = (short)f2bf(b[3]);
  return s;
}

// ---------------- init: transpose weights to [N,K] bf16 ----------------
__global__ void k_transpose_bf16(const float* __restrict__ src, unsigned short* __restrict__ dst,
                                 int R, int C) {
  int id = blockIdx.x * 256 + threadIdx.x;     // over R*C, dst-coalesced
  if (id >= R * C) return;
  int r = id % R, c = id / R;                  // dst[c*R + r] = src[r*C + c]
  dst[id] = f2bf(src[r * C + c]);
}

// Y0 = y_0, y_t[:,0,:] = y_0, t_t = t_eval, y_loss = 0
__global__ void k_init(const float* __restrict__ y0, const float* __restrict__ te,
                       float* __restrict__ Y0, float* __restrict__ out) {
  int id = blockIdx.x * 256 + threadIdx.x;
  if (id < Bsz * Nd) {
    float v = y0[id];
    Y0[id] = v;
    int b = id / Nd, n = id % Nd;
    out[b * (Td * Nd) + n] = v;
  } else if (id < Bsz * Nd + Td) {
    int i = id - Bsz * Nd;
    out[Bsz * Td * Nd + i] = te[i];
  } else if (id < Bsz * Nd + Td + Bsz) {
    int i = id - Bsz * Nd - Td;
    out[Bsz * Td * Nd + Td + i] = 0.0f;
  }
}

// ---------------- kernel A: Z = tanh(U @ W1 + b1), U formed on the fly ----------------
// grid (16 n-tiles, 4 m-tiles), 256 threads = 4 waves (2x2), tile 64Mx128N, BK=64.
// side duties (spread by column slice across n-tiles): Kinit=b2, ACC ops, y/y_t stores.
__launch_bounds__(256)
__global__ void kA(const unsigned short* __restrict__ W1T, const float* __restrict__ b1,
                   const float* __restrict__ b2, const float* __restrict__ te,
                   const float* __restrict__ Yold, float* __restrict__ Ycur,
                   float* __restrict__ ACC, const float* __restrict__ Kprev,
                   float* __restrict__ Kinit, unsigned short* __restrict__ Zbf,
                   float* __restrict__ out, int t, int e) {
  __shared__ unsigned short Ulds[64 * LDU];
  __shared__ unsigned short Wlds[128 * LDU];

  const int tid = threadIdx.x;
  const int m0 = blockIdx.y * 64;
  const int n0 = blockIdx.x * 128;

  const float h = te[t + 1] - te[t];
  float cu = 0.0f;                       // U = Yold + cu*Kprev  (e>=2)
  if (e == 2 || e == 3) cu = 0.5f * h;
  else if (e == 4) cu = h;
  float cf = 0.0f;                       // U = Yold + cf*(ACC+K4)  (e==1, t>0)
  if (e == 1 && t > 0) cf = (te[t] - te[t - 1]) * (1.0f / 6.0f);

  // ---- side duties: this block handles cols [bx*32, bx*32+32) for rows m0..m0+63 ----
  {
    const int cb = blockIdx.x * 32;
    #pragma unroll
    for (int i = 0; i < 2; ++i) {
      int L = tid * 8 + i * 4;               // 0..2044
      int row = L >> 5, colr = L & 31;
      int idx = (m0 + row) * Nd + cb + colr;
      f32x4 bb = *(const f32x4*)&b2[cb + colr];
      *(f32x4*)&Kinit[idx] = bb;             // pre-init k-buffer with bias
      if (e == 2) {
        *(f32x4*)&ACC[idx] = *(const f32x4*)&Kprev[idx];          // ACC = k1
      } else if (e >= 3) {
        f32x4 ac = *(f32x4*)&ACC[idx];
        f32x4 kp = *(const f32x4*)&Kprev[idx];
        ac += 2.0f * kp;                                           // ACC += 2*k2 / 2*k3
        *(f32x4*)&ACC[idx] = ac;
      }
    }
  }

  const int wid = tid >> 6, lane = tid & 63;
  const int wm = wid >> 1, wn = wid & 1;
  const int lr = lane & 15, lk = lane >> 4;

  f32x4 acc[2][4];
  #pragma unroll
  for (int m = 0; m < 2; ++m)
    #pragma unroll
    for (int n = 0; n < 4; ++n) acc[m][n] = (f32x4)0.0f;

  for (int kk = 0; kk < 8; ++kk) {
    const int k0 = kk * 64;
    // ---- stage U tile [64 x 64k] (compute U in f32, cvt bf16) ----
    #pragma unroll
    for (int cc = 0; cc < 2; ++cc) {
      int c = tid + cc * 256;
      int row = c >> 3, kc = c & 7;
      int gr = m0 + row;
      int gk = k0 + kc * 8;
      int gb = gr * Nd + gk;
      f32x4 u0 = *(const f32x4*)&Yold[gb];
      f32x4 u1 = *(const f32x4*)&Yold[gb + 4];
      if (e == 1) {
        if (t > 0) {
          f32x4 a0 = *(const f32x4*)&ACC[gb],  a1 = *(const f32x4*)&ACC[gb + 4];
          f32x4 p0 = *(const f32x4*)&Kprev[gb], p1 = *(const f32x4*)&Kprev[gb + 4];
          u0 += cf * (a0 + p0);
          u1 += cf * (a1 + p1);
          if ((gk >> 5) == blockIdx.x) {       // this block's column slice: persist y_t
            *(f32x4*)&Ycur[gb] = u0; *(f32x4*)&Ycur[gb + 4] = u1;
            int ob = gr * (Td * Nd) + t * Nd + gk;
            *(f32x4*)&out[ob] = u0; *(f32x4*)&out[ob + 4] = u1;
          }
        }
      } else {
        f32x4 p0 = *(const f32x4*)&Kprev[gb], p1 = *(const f32x4*)&Kprev[gb + 4];
        u0 += cu * p0;
        u1 += cu * p1;
      }
      *(short8*)&Ulds[row * LDU + kc * 8] = pack_bf8(u0, u1);
    }
    // ---- stage W1T tile [128 x 64k] ----
    #pragma unroll
    for (int cc = 0; cc < 4; ++cc) {
      int c = tid + cc * 256;
      int row = c >> 3, kc = c & 7;
      int gb = (n0 + row) * Nd + k0 + kc * 8;
      short8 v = *(const short8*)&W1T[gb];
      *(short8*)&Wlds[row * LDU + kc * 8] = v;
    }
    __syncthreads();
    #pragma unroll
    for (int q = 0; q < 2; ++q) {
      short8 av[2], bv[4];
      #pragma unroll
      for (int m = 0; m < 2; ++m)
        av[m] = *(const short8*)&Ulds[(wm * 32 + m * 16 + lr) * LDU + q * 32 + lk * 8];
      #pragma unroll
      for (int n = 0; n < 4; ++n)
        bv[n] = *(const short8*)&Wlds[(wn * 64 + n * 16 + lr) * LDU + q * 32 + lk * 8];
      #pragma unroll
      for (int m = 0; m < 2; ++m)
        #pragma unroll
        for (int n = 0; n < 4; ++n)
          acc[m][n] = __builtin_amdgcn_mfma_f32_16x16x32_bf16(av[m], bv[n], acc[m][n], 0, 0, 0);
    }
    __syncthreads();
  }

  // ---- epilogue: tanh -> Zbf (bf16) ----
  #pragma unroll
  for (int m = 0; m < 2; ++m) {
    int grow = m0 + wm * 32 + m * 16 + lk * 4;
    #pragma unroll
    for (int n = 0; n < 4; ++n) {
      int gcol = n0 + wn * 64 + n * 16 + lr;
      float bias = b1[gcol];
      #pragma unroll
      for (int r = 0; r < 4; ++r) {
        float z = tanhf(acc[m][n][r] + bias);
        Zbf[(grow + r) * Hd + gcol] = f2bf(z);
      }
    }
  }
}

// ---------------- kernel B: Kout += Z @ W2 (split-K, atomic) ----------------
// grid (8 n-tiles, 4 m-tiles, 4 k-chunks), 256 threads = 4 waves (2x2), tile 64x64, BK=64.
__launch_bounds__(256)
__global__ void kB(const unsigned short* __restrict__ Zbf, const unsigned short* __restrict__ W2T,
                   float* __restrict__ Kout) {
  __shared__ unsigned short Alds[64 * LDU];
  __shared__ unsigned short Blds[64 * LDU];

  const int tid = threadIdx.x;
  const int m0 = blockIdx.y * 64;
  const int n0 = blockIdx.x * 64;
  const int kbase = blockIdx.z * 512;
  const int wid = tid >> 6, lane = tid & 63;
  const int wm = wid >> 1, wn = wid & 1;
  const int lr = lane & 15, lk = lane >> 4;

  f32x4 acc[2][2];
  #pragma unroll
  for (int m = 0; m < 2; ++m)
    #pragma unroll
    for (int n = 0; n < 2; ++n) acc[m][n] = (f32x4)0.0f;

  for (int kk = 0; kk < 8; ++kk) {
    const int k0 = kbase + kk * 64;
    #pragma unroll
    for (int cc = 0; cc < 2; ++cc) {
      int c = tid + cc * 256;
      int row = c >> 3, kc = c & 7;
      short8 va = *(const short8*)&Zbf[(m0 + row) * Hd + k0 + kc * 8];
      *(short8*)&Alds[row * LDU + kc * 8] = va;
      short8 vb = *(const short8*)&W2T[(n0 + row) * Hd + k0 + kc * 8];
      *(short8*)&Blds[row * LDU + kc * 8] = vb;
    }
    __syncthreads();
    #pragma unroll
    for (int q = 0; q < 2; ++q) {
      short8 av[2], bv[2];
      #pragma unroll
      for (int m = 0; m < 2; ++m)
        av[m] = *(const short8*)&Alds[(wm * 32 + m * 16 + lr) * LDU + q * 32 + lk * 8];
      #pragma unroll
      for (int n = 0; n < 2; ++n)
        bv[n] = *(const short8*)&Blds[(wn * 32 + n * 16 + lr) * LDU + q * 32 + lk * 8];
      #pragma unroll
      for (int m = 0; m < 2; ++m)
        #pragma unroll
        for (int n = 0; n < 2; ++n)
          acc[m][n] = __builtin_amdgcn_mfma_f32_16x16x32_bf16(av[m], bv[n], acc[m][n], 0, 0, 0);
    }
    __syncthreads();
  }

  #pragma unroll
  for (int m = 0; m < 2; ++m) {
    int grow = m0 + wm * 32 + m * 16 + lk * 4;
    #pragma unroll
    for (int n = 0; n < 2; ++n) {
      int gcol = n0 + wn * 32 + n * 16 + lr;
      #pragma unroll
      for (int r = 0; r < 4; ++r)
        atomicAdd(&Kout[(grow + r) * Nd + gcol], acc[m][n][r]);
    }
  }
}

// ---------------- finish: y_63 = y_62 + h/6*(ACC + k4) ----------------
__global__ void k_finish(const float* __restrict__ te, const float* __restrict__ Ylast,
                         const float* __restrict__ ACC, const float* __restrict__ K4,
                         float* __restrict__ out) {
  int id = blockIdx.x * 256 + threadIdx.x;
  if (id >= Bsz * Nd) return;
  float h = te[Td - 1] - te[Td - 2];
  float v = Ylast[id] + (h * (1.0f / 6.0f)) * (ACC[id] + K4[id]);
  out[(id / Nd) * (Td * Nd) + (Td - 1) * Nd + (id % Nd)] = v;
}

extern "C" void kernel_launch(void* const* d_in, const int* in_sizes, int n_in,
                              void* d_out, int out_size, void* d_ws, size_t ws_size,
                              hipStream_t stream) {
  const float* y0 = (const float*)d_in[0];
  const float* te = (const float*)d_in[1];
  const float* W1 = (const float*)d_in[2];
  const float* b1 = (const float*)d_in[3];
  const float* W2 = (const float*)d_in[4];
  const float* b2 = (const float*)d_in[5];
  float* out = (float*)d_out;

  char* p = (char*)d_ws;
  unsigned short* W1T = (unsigned short*)p; p += (size_t)Hd * Nd * 2;
  unsigned short* W2T = (unsigned short*)p; p += (size_t)Nd * Hd * 2;
  unsigned short* Zbf = (unsigned short*)p; p += (size_t)Bsz * Hd * 2;
  float* Yb[2];
  Yb[0] = (float*)p; p += (size_t)Bsz * Nd * 4;
  Yb[1] = (float*)p; p += (size_t)Bsz * Nd * 4;
  float* ACC = (float*)p; p += (size_t)Bsz * Nd * 4;
  float* Kb[4];
  for (int i = 0; i < 4; ++i) { Kb[i] = (float*)p; p += (size_t)Bsz * Nd * 4; }

  // init
  k_transpose_bf16<<<(Hd * Nd + 255) / 256, 256, 0, stream>>>(W1, W1T, Nd, Hd); // W1[512,2048] -> W1T[2048,512]
  k_transpose_bf16<<<(Hd * Nd + 255) / 256, 256, 0, stream>>>(W2, W2T, Hd, Nd); // W2[2048,512] -> W2T[512,2048]
  k_init<<<(Bsz * Nd + Td + Bsz + 255) / 256, 256, 0, stream>>>(y0, te, Yb[0], out);

  for (int t = 0; t < Td - 1; ++t) {
    int par = t & 1;
    for (int e = 1; e <= 4; ++e) {
      const float* Yold = (e == 1) ? ((t == 0) ? Yb[0] : Yb[1 - par]) : Yb[par];
      const float* Kprev = (e == 1) ? Kb[3] : Kb[e - 2];
      kA<<<dim3(Hd / 128, Bsz / 64), 256, 0, stream>>>(W1T, b1, b2, te, Yold, Yb[par],
                                                       ACC, Kprev, Kb[e - 1], Zbf, out, t, e);
      kB<<<dim3(Nd / 64, Bsz / 64, 4), 256, 0, stream>>>(Zbf, W2T, Kb[e - 1]);
    }
  }
  k_finish<<<(Bsz * Nd + 255) / 256, 256, 0, stream>>>(te, Yb[(Td - 2) & 1], ACC, Kb[3], out);
}

// Round 3
// 5010.581 us; speedup vs baseline: 1.4098x; 1.4098x over previous
//
#include <hip/hip_runtime.h>
#include <hip/hip_bf16.h>

#define Bsz 256
#define Nd  512
#define Hd  2048
#define Td  64
#define KSZ (Bsz * Nd)
#define OFF_T (Bsz * Td * Nd)
#define OFF_L (OFF_T + Td)
#define LDU 520   // Ulds row stride (elements)
#define LDZ 136   // Zlds row stride
#define NBLK 256

typedef __attribute__((ext_vector_type(8))) short short8;
typedef __attribute__((ext_vector_type(4))) float f32x4;

static __device__ __forceinline__ unsigned short f2bf(float x) {
  unsigned u = __builtin_bit_cast(unsigned, x);
  u += 0x7FFFu + ((u >> 16) & 1u);   // RNE
  return (unsigned short)(u >> 16);
}

static __device__ __forceinline__ float fast_tanh(float x) {
  float ex = __expf(2.0f * x);           // inf-safe: ex=inf -> 1, ex=0 -> -1
  return 1.0f - 2.0f / (ex + 1.0f);
}

static __device__ __forceinline__ unsigned long long ld_agent_u64(const float* p) {
  return __hip_atomic_load((const unsigned long long*)p, __ATOMIC_RELAXED,
                           __HIP_MEMORY_SCOPE_AGENT);
}

// hand-rolled grid barrier: monotonic counter, target = phase*NBLK
static __device__ __forceinline__ void gbar(unsigned* bar, unsigned target) {
  __syncthreads();                     // drains vmem: all this block's atomics done
  if (threadIdx.x == 0) {
    __hip_atomic_fetch_add(bar, 1u, __ATOMIC_ACQ_REL, __HIP_MEMORY_SCOPE_AGENT);
    while (__hip_atomic_load(bar, __ATOMIC_ACQUIRE, __HIP_MEMORY_SCOPE_AGENT) < target) {
      __builtin_amdgcn_s_sleep(2);
    }
  }
  __syncthreads();
}

// Persistent kernel. 256 blocks x 256 threads (4 waves), 1 block/CU (LDS-forced).
// block = (im = blk&15: 16-row m-slice, ih = blk>>4: 128-col H-slice).
// Weights live in registers for the whole integration; 1 grid barrier per f-eval.
__launch_bounds__(256, 1)
__global__ void ode_persistent(const float* __restrict__ y0g, const float* __restrict__ te,
                               const float* __restrict__ W1, const float* __restrict__ b1,
                               const float* __restrict__ W2, const float* __restrict__ b2,
                               float* __restrict__ out, float* __restrict__ kbuf,
                               unsigned* __restrict__ bar) {
  __shared__ unsigned short Ulds[16 * LDU];
  __shared__ unsigned short Zlds[16 * LDZ];
  extern __shared__ char dpad[];       // 62KB dynamic pad -> forces 1 block/CU

  const int blk = blockIdx.x;
  const int im = blk & 15, ih = blk >> 4;
  const int tid = threadIdx.x;
  const int wv = tid >> 6, lane = tid & 63;
  const int lr = lane & 15, lk = lane >> 4;

  if (te[0] == 1.0e30f) dpad[tid] = 1; // never true; keeps dynamic-LDS request live

  // ---------- one-time: load resident weight fragments (bf16) ----------
  short8 w1f[2][16];
  {
    const int hbase = ih * 128 + wv * 32;
    #pragma unroll
    for (int n = 0; n < 2; ++n) {
      const int col = hbase + n * 16 + lr;
      #pragma unroll
      for (int kt = 0; kt < 16; ++kt) {
        short8 v;
        #pragma unroll
        for (int j = 0; j < 8; ++j)
          v[j] = (short)f2bf(W1[(kt * 32 + lk * 8 + j) * Hd + col]);
        w1f[n][kt] = v;
      }
    }
  }
  short8 w2f[8][4];
  {
    #pragma unroll
    for (int n = 0; n < 8; ++n) {
      const int col = wv * 128 + n * 16 + lr;
      #pragma unroll
      for (int kt = 0; kt < 4; ++kt) {
        short8 v;
        #pragma unroll
        for (int j = 0; j < 8; ++j)
          v[j] = (short)f2bf(W2[(ih * 128 + kt * 32 + lk * 8 + j) * Nd + col]);
        w2f[n][kt] = v;
      }
    }
  }
  float b1c[2];
  {
    const int hbase = ih * 128 + wv * 32;
    b1c[0] = b1[hbase + lr];
    b1c[1] = b1[hbase + 16 + lr];
  }

  // ---------- per-thread state mapping ----------
  const int r  = tid >> 4;            // local m-row 0..15
  const int cq = tid & 15;
  const int cb = cq * 32;             // this thread's 32-col chunk of N
  const int rowg = im * 16 + r;       // global batch row
  const int colI = ih * 32 + cq * 2;  // this block's init-chunk col

  const float b2c0 = b2[colI], b2c1 = b2[colI + 1];
  const unsigned long long b2pk =
      ((unsigned long long)__builtin_bit_cast(unsigned, b2c1) << 32) |
      __builtin_bit_cast(unsigned, b2c0);

  float yv[32];
  #pragma unroll
  for (int g = 0; g < 8; ++g) {
    f32x4 v = *(const f32x4*)&y0g[rowg * Nd + cb + g * 4];
    yv[g * 4 + 0] = v[0]; yv[g * 4 + 1] = v[1];
    yv[g * 4 + 2] = v[2]; yv[g * 4 + 3] = v[3];
  }
  float acc_y[32];
  #pragma unroll
  for (int p = 0; p < 32; ++p) acc_y[p] = 0.0f;

  // ---------- pre-loop outputs ----------
  if (cq == ih) {                      // y_t[:, 0, :]
    #pragma unroll
    for (int g = 0; g < 8; ++g) {
      f32x4 v = {yv[g * 4], yv[g * 4 + 1], yv[g * 4 + 2], yv[g * 4 + 3]};
      *(f32x4*)&out[rowg * (Td * Nd) + cb + g * 4] = v;
    }
  }
  if (blk == 0) {                      // t_t and y_loss
    if (tid < Td) out[OFF_T + tid] = te[tid];
    out[OFF_L + tid] = 0.0f;
  }
  // init k-buffer 0 with b2 (coherent store)
  __hip_atomic_store((unsigned long long*)&kbuf[rowg * Nd + colI], b2pk,
                     __ATOMIC_RELAXED, __HIP_MEMORY_SCOPE_AGENT);
  unsigned phase = 1;
  gbar(bar, phase * NBLK);

  // ---------- main integration loop: 63 steps x 4 evals ----------
  int j = 0;
  for (int t = 0; t < Td - 1; ++t) {
    const float h = te[t + 1] - te[t];
    for (int e = 1; e <= 4; ++e) {
      float* bufc = kbuf + (j % 3) * KSZ;
      float* bufn = kbuf + ((j + 1) % 3) * KSZ;
      const float* bufp = kbuf + ((j + 2) % 3) * KSZ;   // == (j-1) mod 3

      // ---- U phase: form U (bf16) in LDS; maintain y / acc_y ----
      if (e == 1) {
        if (t > 0) {
          const float hp6 = (te[t] - te[t - 1]) * (1.0f / 6.0f);
          #pragma unroll
          for (int g = 0; g < 4; ++g) {
            #pragma unroll
            for (int p = 0; p < 4; ++p) {
              unsigned long long q = ld_agent_u64(&bufp[rowg * Nd + cb + g * 8 + p * 2]);
              float k0 = __builtin_bit_cast(float, (unsigned)(q & 0xFFFFFFFFull));
              float k1 = __builtin_bit_cast(float, (unsigned)(q >> 32));
              yv[g * 8 + p * 2 + 0] += hp6 * (acc_y[g * 8 + p * 2 + 0] + k0);
              yv[g * 8 + p * 2 + 1] += hp6 * (acc_y[g * 8 + p * 2 + 1] + k1);
            }
          }
          if (cq == ih) {              // y_t[:, t, :]
            #pragma unroll
            for (int g = 0; g < 8; ++g) {
              f32x4 v = {yv[g * 4], yv[g * 4 + 1], yv[g * 4 + 2], yv[g * 4 + 3]};
              *(f32x4*)&out[rowg * (Td * Nd) + t * Nd + cb + g * 4] = v;
            }
          }
        }
        #pragma unroll
        for (int p = 0; p < 32; ++p) acc_y[p] = 0.0f;
        #pragma unroll
        for (int g = 0; g < 4; ++g) {
          short8 s;
          #pragma unroll
          for (int p = 0; p < 8; ++p) s[p] = (short)f2bf(yv[g * 8 + p]);
          *(short8*)&Ulds[r * LDU + cb + g * 8] = s;
        }
      } else {
        const float c = (e == 4) ? h : 0.5f * h;
        const float w = (e == 2) ? 1.0f : 2.0f;
        #pragma unroll
        for (int g = 0; g < 4; ++g) {
          short8 s;
          #pragma unroll
          for (int p = 0; p < 4; ++p) {
            unsigned long long q = ld_agent_u64(&bufp[rowg * Nd + cb + g * 8 + p * 2]);
            float k0 = __builtin_bit_cast(float, (unsigned)(q & 0xFFFFFFFFull));
            float k1 = __builtin_bit_cast(float, (unsigned)(q >> 32));
            acc_y[g * 8 + p * 2 + 0] += w * k0;
            acc_y[g * 8 + p * 2 + 1] += w * k1;
            float u0 = yv[g * 8 + p * 2 + 0] + c * k0;
            float u1 = yv[g * 8 + p * 2 + 1] + c * k1;
            s[p * 2 + 0] = (short)f2bf(u0);
            s[p * 2 + 1] = (short)f2bf(u1);
          }
          *(short8*)&Ulds[r * LDU + cb + g * 8] = s;
        }
      }
      // pre-init NEXT eval's k-buffer with b2 (its readers finished >=1 barrier ago)
      __hip_atomic_store((unsigned long long*)&bufn[rowg * Nd + colI], b2pk,
                         __ATOMIC_RELAXED, __HIP_MEMORY_SCOPE_AGENT);
      __syncthreads();

      // ---- GEMM1: acc1[16 x 32cols] = U[16,512] @ W1slice, resident B-frags ----
      f32x4 acc1_0 = {0.f, 0.f, 0.f, 0.f}, acc1_1 = {0.f, 0.f, 0.f, 0.f};
      {
        const int abase = lr * LDU + lk * 8;
        #pragma unroll
        for (int kt = 0; kt < 16; ++kt) {
          short8 a = *(const short8*)&Ulds[abase + kt * 32];
          acc1_0 = __builtin_amdgcn_mfma_f32_16x16x32_bf16(a, w1f[0][kt], acc1_0, 0, 0, 0);
          acc1_1 = __builtin_amdgcn_mfma_f32_16x16x32_bf16(a, w1f[1][kt], acc1_1, 0, 0, 0);
        }
      }
      // ---- tanh -> Zlds (bf16) ----
      #pragma unroll
      for (int n = 0; n < 2; ++n) {
        f32x4 a = n ? acc1_1 : acc1_0;
        #pragma unroll
        for (int q = 0; q < 4; ++q) {
          float z = fast_tanh(a[q] + b1c[n]);
          Zlds[(lk * 4 + q) * LDZ + wv * 32 + n * 16 + lr] = f2bf(z);
        }
      }
      __syncthreads();

      // ---- GEMM2: k-partial[16 x 128cols] = Z[16,128] @ W2slice ----
      f32x4 acc2[8];
      #pragma unroll
      for (int n = 0; n < 8; ++n) acc2[n] = (f32x4){0.f, 0.f, 0.f, 0.f};
      {
        const int zbase = lr * LDZ + lk * 8;
        #pragma unroll
        for (int kt = 0; kt < 4; ++kt) {
          short8 a = *(const short8*)&Zlds[zbase + kt * 32];
          #pragma unroll
          for (int n = 0; n < 8; ++n)
            acc2[n] = __builtin_amdgcn_mfma_f32_16x16x32_bf16(a, w2f[n][kt], acc2[n], 0, 0, 0);
        }
      }
      // ---- H-reduction across the 16 ih-blocks: device-coherent f32 atomics ----
      #pragma unroll
      for (int n = 0; n < 8; ++n) {
        const int colA = wv * 128 + n * 16 + lr;
        #pragma unroll
        for (int q = 0; q < 4; ++q)
          unsafeAtomicAdd(&bufc[(im * 16 + lk * 4 + q) * Nd + colA], acc2[n][q]);
      }
      ++phase;
      gbar(bar, phase * NBLK);
      ++j;
    }
  }

  // ---------- epilogue: final y-update + y_t[:, 63, :] ----------
  {
    const float* bufp = kbuf + ((j + 2) % 3) * KSZ;
    const float hp6 = (te[Td - 1] - te[Td - 2]) * (1.0f / 6.0f);
    #pragma unroll
    for (int g = 0; g < 4; ++g) {
      #pragma unroll
      for (int p = 0; p < 4; ++p) {
        unsigned long long q = ld_agent_u64(&bufp[rowg * Nd + cb + g * 8 + p * 2]);
        float k0 = __builtin_bit_cast(float, (unsigned)(q & 0xFFFFFFFFull));
        float k1 = __builtin_bit_cast(float, (unsigned)(q >> 32));
        yv[g * 8 + p * 2 + 0] += hp6 * (acc_y[g * 8 + p * 2 + 0] + k0);
        yv[g * 8 + p * 2 + 1] += hp6 * (acc_y[g * 8 + p * 2 + 1] + k1);
      }
    }
    if (cq == ih) {
      #pragma unroll
      for (int g = 0; g < 8; ++g) {
        f32x4 v = {yv[g * 4], yv[g * 4 + 1], yv[g * 4 + 2], yv[g * 4 + 3]};
        *(f32x4*)&out[rowg * (Td * Nd) + (Td - 1) * Nd + cb + g * 4] = v;
      }
    }
  }
}

extern "C" void kernel_launch(void* const* d_in, const int* in_sizes, int n_in,
                              void* d_out, int out_size, void* d_ws, size_t ws_size,
                              hipStream_t stream) {
  const float* y0 = (const float*)d_in[0];
  const float* te = (const float*)d_in[1];
  const float* W1 = (const float*)d_in[2];
  const float* b1 = (const float*)d_in[3];
  const float* W2 = (const float*)d_in[4];
  const float* b2 = (const float*)d_in[5];
  float* out = (float*)d_out;
  float* kbuf = (float*)d_ws;                    // 3 rotating k-buffers, 1.5 MB
  unsigned* bar = (unsigned*)((char*)d_ws + 3 * (size_t)KSZ * 4);

  hipMemsetAsync(bar, 0, 4, stream);             // reset barrier counter (capture-safe)
  ode_persistent<<<dim3(NBLK), dim3(256), 62 * 1024, stream>>>(
      y0, te, W1, b1, W2, b2, out, kbuf, bar);
}